// Round 5
// baseline (105.205 us; speedup 1.0000x reference)
//
#include <hip/hip_runtime.h>
#include <math.h>

constexpr int C = 512;
constexpr int H = 50;
constexpr int W = 75;
constexpr int NROI = 512;
constexpr int PLANE = H * W;      // 3750
constexpr int PXP   = 3840;       // padded pixel count (pad rows zeroed)
constexpr int SLAB  = 256;        // channels per main-kernel block
constexpr int NSLAB = C / SLAB;   // 2
constexpr int RESP  = 260;        // res row pitch (floats), padded
constexpr float INV_STRIDE = 1.0f / 16.0f;

typedef _Float16 h2 __attribute__((ext_vector_type(2)));
struct px4 { h2 a, b; };          // 4 consecutive fp16 channels of one pixel (8 B)

// ---------------------------------------------------------------------------
// Transpose prepass: bottom [512 ch][3750 px] f32 -> P [3840 px][512 ch] f16.
// 64x64 tiles through LDS; both global sides coalesced. Pad pixels zeroed so
// zero-weight OOB corners read harmless values.
// ---------------------------------------------------------------------------
__global__ __launch_bounds__(256) void transpose_kernel(const float* __restrict__ bottom,
                                                        _Float16* __restrict__ P)
{
    __shared__ _Float16 tile[64][66];   // pad 66: phase-2 column reads conflict-free
    int px0 = blockIdx.x * 64;
    int c0  = blockIdx.y * 64;
    int tx = threadIdx.x & 63;
    int ty = threadIdx.x >> 6;          // 0..3
#pragma unroll
    for (int k = 0; k < 16; ++k) {
        int cl = ty + 4 * k;
        int px = px0 + tx;
        float v = (px < PLANE) ? bottom[(c0 + cl) * PLANE + px] : 0.0f;
        tile[cl][tx] = (_Float16)v;     // lanes -> consecutive LDS halfwords
    }
    __syncthreads();
#pragma unroll
    for (int k = 0; k < 16; ++k) {
        int pl = ty + 4 * k;
        P[(px0 + pl) * C + c0 + tx] = tile[tx][pl];  // 128 B coalesced store
    }
}

// ---------------------------------------------------------------------------
// Main: block = (roi, 256-ch slab). Lane = 4-channel group; all lanes of a
// wave share the output position, so corner pixel addresses are wave-uniform
// -> each corner read is one coalesced 512 B global_load_dwordx2 (L1/L2 hit,
// zero LDS bank conflicts). Results staged in LDS, stored coalesced.
// ---------------------------------------------------------------------------
struct Desc { int off; h2 w0s; h2 w1s; };   // offset (col, or row*75), splatted weights

__global__ __launch_bounds__(256) void roialign_main(const _Float16* __restrict__ P,
                                                     const float* __restrict__ rois,
                                                     float* __restrict__ out)
{
    __shared__ Desc xdesc[14], ydesc[14];
    __shared__ float res[49 * RESP];    // [s49][RESP]; ch c at res[s*RESP + c]

    int roi  = blockIdx.x;
    int slab = blockIdx.y;
    int t    = threadIdx.x;

    // Per-ROI interpolation descriptors (same math as the passing R1/R2/R4 kernels)
    if (t < 28) {
        bool isx = t < 14;
        int j = isx ? t : t - 14;
        const float* r = rois + roi * 5;
        float lo = (isx ? r[1] : r[2]) * INV_STRIDE;
        float hi = (isx ? r[3] : r[4]) * INV_STRIDE;
        float cc = 0.5f * (lo + hi), dd = 0.5f * (hi - lo);
        float b = -1.0f + (2.0f / 13.0f) * (float)j;
        float x  = fmaf(dd, b, cc);
        float xf = floorf(x);
        int ix = (int)xf;
        float f = x - xf;
        int lim = isx ? (W - 1) : (H - 1);
        bool v0 = (ix >= 0) && (ix <= lim);
        bool v1 = (ix + 1 >= 0) && (ix + 1 <= lim);
        int off = min(max(ix, 0), lim) * (isx ? 1 : W);
        float w0 = v0 ? (1.0f - f) : 0.0f;
        float w1 = v1 ? f : 0.0f;
        Desc d;
        d.off = off;
        d.w0s = (h2){(_Float16)w0, (_Float16)w0};
        d.w1s = (h2){(_Float16)w1, (_Float16)w1};
        (isx ? xdesc : ydesc)[j] = d;
    }
    __syncthreads();

    int lane = t & 63;
    int wv   = t >> 6;
    const px4* P4 = (const px4*)P;      // 128 px4 per pixel
    int lbase = slab * 64 + lane;       // px4 index within a pixel (ch = 4*lbase)

    for (int s49 = wv; s49 < 49; s49 += 4) {
        int ph = s49 / 7;
        int pw = s49 - ph * 7;
        Desc xd0 = xdesc[2 * pw], xd1 = xdesc[2 * pw + 1];
        Desc yd0 = ydesc[2 * ph], yd1 = ydesc[2 * ph + 1];

        px4 acc;
        acc.a = (h2){(_Float16)(-65504.0f), (_Float16)(-65504.0f)};
        acc.b = acc.a;

        auto sample = [&](const Desc& yd, const Desc& xd) {
            int pix = __builtin_amdgcn_readfirstlane(yd.off + xd.off);  // wave-uniform
            const px4* p = P4 + pix * 128 + lbase;
            px4 q00 = p[0];          // coalesced 512 B segments, lane-stride 8 B
            px4 q01 = p[128];        // x+1
            px4 q10 = p[75 * 128];   // y+1
            px4 q11 = p[76 * 128];   // x+1, y+1  (pad pixels zeroed; weight 0)
            h2 r0a = xd.w0s * q00.a + xd.w1s * q01.a;
            h2 r0b = xd.w0s * q00.b + xd.w1s * q01.b;
            h2 r1a = xd.w0s * q10.a + xd.w1s * q11.a;
            h2 r1b = xd.w0s * q10.b + xd.w1s * q11.b;
            h2 va = yd.w0s * r0a + yd.w1s * r1a;
            h2 vb = yd.w0s * r0b + yd.w1s * r1b;
            acc.a = __builtin_elementwise_max(acc.a, va);
            acc.b = __builtin_elementwise_max(acc.b, vb);
        };
        sample(yd0, xd0);
        sample(yd0, xd1);
        sample(yd1, xd0);
        sample(yd1, xd1);

        float4 v4 = {(float)acc.a.x, (float)acc.a.y, (float)acc.b.x, (float)acc.b.y};
        *(float4*)(res + s49 * RESP + 4 * lane) = v4;   // conflict-free (contiguous)
    }
    __syncthreads();

    // Coalesced store: out[(roi*C + slab*SLAB + c)*49 + s49]
    float* ob = out + (size_t)(roi * C + slab * SLAB) * 49;
    for (int idx = t; idx < SLAB * 49; idx += 256) {
        int c = idx / 49;
        int s = idx - c * 49;
        ob[idx] = res[s * RESP + c];
    }
}

extern "C" void kernel_launch(void* const* d_in, const int* in_sizes, int n_in,
                              void* d_out, int out_size, void* d_ws, size_t ws_size,
                              hipStream_t stream) {
    const float* bottom = (const float*)d_in[0];
    const float* rois   = (const float*)d_in[1];
    float* out = (float*)d_out;

    _Float16* P = (_Float16*)d_ws;      // 3840 * 512 * 2 B = 3.93 MB

    dim3 tgrid(PXP / 64, C / 64);       // 60 x 8
    transpose_kernel<<<tgrid, 256, 0, stream>>>(bottom, P);

    dim3 mgrid(NROI, NSLAB);            // 512 x 2
    roialign_main<<<mgrid, 256, 0, stream>>>(P, rois, out);
}

// Round 6
// 103.908 us; speedup vs baseline: 1.0125x; 1.0125x over previous
//
#include <hip/hip_runtime.h>
#include <math.h>

constexpr int C = 512;
constexpr int H = 50;
constexpr int W = 75;
constexpr int NROI = 512;
constexpr int PLANE = H * W;      // 3750
constexpr int PXP   = 3840;       // padded pixel count (pad pixels zeroed)
constexpr int SLAB  = 64;         // channels per main-kernel block
constexpr int NSLAB = C / SLAB;   // 8
constexpr int GPP   = SLAB / 4;   // 16 px4 groups per slab
constexpr int RESP  = 65;         // res row pitch (floats), ODD -> conflict-free readout
constexpr float INV_STRIDE = 1.0f / 16.0f;

typedef _Float16 h2 __attribute__((ext_vector_type(2)));
struct px4 { h2 a, b; };          // 4 consecutive fp16 channels of one pixel (8 B)

// ---------------------------------------------------------------------------
// Transpose prepass: bottom [512 ch][3750 px] f32 -> P [3840 px][512 ch] f16.
// 64x64 tiles through LDS; both global sides coalesced. Pad pixels zeroed so
// zero-weight OOB corners read harmless values.
// ---------------------------------------------------------------------------
__global__ __launch_bounds__(256) void transpose_kernel(const float* __restrict__ bottom,
                                                        _Float16* __restrict__ P)
{
    __shared__ _Float16 tile[64][66];
    int px0 = blockIdx.x * 64;
    int c0  = blockIdx.y * 64;
    int tx = threadIdx.x & 63;
    int ty = threadIdx.x >> 6;          // 0..3
#pragma unroll
    for (int k = 0; k < 16; ++k) {
        int cl = ty + 4 * k;
        int px = px0 + tx;
        float v = (px < PLANE) ? bottom[(c0 + cl) * PLANE + px] : 0.0f;
        tile[cl][tx] = (_Float16)v;
    }
    __syncthreads();
#pragma unroll
    for (int k = 0; k < 16; ++k) {
        int pl = ty + 4 * k;
        P[(px0 + pl) * C + c0 + tx] = tile[tx][pl];  // 128 B coalesced store
    }
}

// ---------------------------------------------------------------------------
// Main: block = (roi, 64-ch slab); grid 512 x 8 = 4096 (16 blocks/CU, 2 clean
// occupancy rounds at the 32-wave/CU cap). Lane = (pos-quad 2b | ch-group 4b):
// each wave processes 4 output positions at once -> every corner read is one
// global load of 4 x 128 B contiguous segments (coalesced, zero LDS bank
// conflicts), 16 loads in flight per iteration. Results staged in LDS with an
// odd pitch, then stored coalesced in [C][49] order.
// ---------------------------------------------------------------------------
struct Desc { int off; h2 w0s; h2 w1s; };   // offset (col, or row*75), splatted weights

__global__ __launch_bounds__(256, 8) void roialign_main(const px4* __restrict__ P4,
                                                        const float* __restrict__ rois,
                                                        float* __restrict__ out)
{
    __shared__ Desc xdesc[14], ydesc[14];
    __shared__ float res[49 * RESP];        // 12740 B

    int roi  = blockIdx.x;
    int slab = blockIdx.y;
    int t    = threadIdx.x;

    // Per-ROI interpolation descriptors (same math as the passing R1/R2/R4 kernels)
    if (t < 28) {
        bool isx = t < 14;
        int j = isx ? t : t - 14;
        const float* r = rois + roi * 5;
        float lo = (isx ? r[1] : r[2]) * INV_STRIDE;
        float hi = (isx ? r[3] : r[4]) * INV_STRIDE;
        float cc = 0.5f * (lo + hi), dd = 0.5f * (hi - lo);
        float b = -1.0f + (2.0f / 13.0f) * (float)j;
        float x  = fmaf(dd, b, cc);
        float xf = floorf(x);
        int ix = (int)xf;
        float f = x - xf;
        int lim = isx ? (W - 1) : (H - 1);
        bool v0 = (ix >= 0) && (ix <= lim);
        bool v1 = (ix + 1 >= 0) && (ix + 1 <= lim);
        int off = min(max(ix, 0), lim) * (isx ? 1 : W);
        float w0 = v0 ? (1.0f - f) : 0.0f;
        float w1 = v1 ? f : 0.0f;
        Desc d;
        d.off = off;
        d.w0s = (h2){(_Float16)w0, (_Float16)w0};
        d.w1s = (h2){(_Float16)w1, (_Float16)w1};
        (isx ? xdesc : ydesc)[j] = d;
    }
    __syncthreads();

    int lane = t & 63;
    int wv   = t >> 6;
    int g    = lane & 15;               // px4 group within the 64-ch slab
    int pq   = lane >> 4;               // 0..3 position offset within the quad
    int base = slab * GPP + g;          // px4 index within a pixel

    for (int pg = wv; pg < 13; pg += 4) {
        int s49 = min(4 * pg + pq, 48); // tail lanes duplicate pos 48 (benign: same value, same addr)
        int ph = s49 / 7;
        int pw = s49 - ph * 7;
        Desc xd0 = xdesc[2 * pw], xd1 = xdesc[2 * pw + 1];
        Desc yd0 = ydesc[2 * ph], yd1 = ydesc[2 * ph + 1];

        auto sample = [&](const Desc& yd, const Desc& xd) -> px4 {
            int pix = yd.off + xd.off;
            const px4* p = P4 + pix * 128 + base;
            px4 q00 = p[0];
            px4 q01 = p[128];          // x+1
            px4 q10 = p[75 * 128];     // y+1
            px4 q11 = p[76 * 128];     // x+1, y+1 (pad pixels zeroed; weight 0)
            px4 v;
            v.a = yd.w0s * (xd.w0s * q00.a + xd.w1s * q01.a)
                + yd.w1s * (xd.w0s * q10.a + xd.w1s * q11.a);
            v.b = yd.w0s * (xd.w0s * q00.b + xd.w1s * q01.b)
                + yd.w1s * (xd.w0s * q10.b + xd.w1s * q11.b);
            return v;
        };

        // two phases to bound live registers (<=64 VGPR @ 8 waves/SIMD)
        px4 s0 = sample(yd0, xd0);
        px4 s1 = sample(yd0, xd1);
        px4 m;
        m.a = __builtin_elementwise_max(s0.a, s1.a);
        m.b = __builtin_elementwise_max(s0.b, s1.b);
        px4 s2 = sample(yd1, xd0);
        px4 s3 = sample(yd1, xd1);
        m.a = __builtin_elementwise_max(m.a, __builtin_elementwise_max(s2.a, s3.a));
        m.b = __builtin_elementwise_max(m.b, __builtin_elementwise_max(s2.b, s3.b));

        float* rp = res + s49 * RESP + 4 * g;
        rp[0] = (float)m.a.x;
        rp[1] = (float)m.a.y;
        rp[2] = (float)m.b.x;
        rp[3] = (float)m.b.y;
    }
    __syncthreads();

    // Coalesced store: out[(roi*C + slab*64 + c)*49 + s]
    float* ob = out + (size_t)(roi * C + slab * SLAB) * 49;
    for (int idx = t; idx < SLAB * 49; idx += 256) {
        int c = idx / 49;
        int s = idx - c * 49;
        ob[idx] = res[s * RESP + c];    // bank stride 1 across lanes (RESP odd)
    }
}

extern "C" void kernel_launch(void* const* d_in, const int* in_sizes, int n_in,
                              void* d_out, int out_size, void* d_ws, size_t ws_size,
                              hipStream_t stream) {
    const float* bottom = (const float*)d_in[0];
    const float* rois   = (const float*)d_in[1];
    float* out = (float*)d_out;

    _Float16* P = (_Float16*)d_ws;      // 3840 * 512 * 2 B = 3.93 MB

    dim3 tgrid(PXP / 64, C / 64);       // 60 x 8
    transpose_kernel<<<tgrid, 256, 0, stream>>>(bottom, P);

    dim3 mgrid(NROI, NSLAB);            // 512 x 8 = 4096 blocks
    roialign_main<<<mgrid, 256, 0, stream>>>((const px4*)P, rois, out);
}